// Round 7
// baseline (41.581 us; speedup 1.0000x reference)
//
#include <hip/hip_runtime.h>
#include <hip/hip_bf16.h>

// ARD kernel matrix: out[i][j] = exp(-0.5 * sum_d (x[i][d]-y[j][d])^2 / exp(lbw[d]))
// Quadratic expansion: weight rows by exp(-0.5*lbw), cast bf16, MFMA GEMM for the
// cross term, fused epilogue exp(-0.5*(x2+y2-2*cross)).
//
// Round 7: WRITE DRAM LOCALITY. R1-R6 invariant: 128x128 tiles -> 512B write
// segments at 16KB stride -> ~1.6-2.2 TB/s DRAM write ceiling regardless of
// kernel internals (R5 counter: 1.57 TB/s vs 6.2 for linear fills). New:
// (a) 32x512 tiles -> 2KB contiguous segments; (b) XCD slab mapping -- each
// XCD owns a 512-row slab, resident blocks cover COMPLETE output rows, so
// L2 evictions stream full 16KB rows. Compute keeps R6's verified pieces.

typedef __attribute__((ext_vector_type(8))) short bf16x8;   // 8 bf16 = 4 VGPRs
typedef __attribute__((ext_vector_type(4))) float f32x4;    // MFMA accumulator

#define NN 4096
#define MM 4096
#define DD 256

#define BM 32
#define BN 512
#define BK 32            // K-step; 64 B per LDS row
#define NKT (DD / BK)    // 8

#define GLOAD16(gp, lp)                                                        \
    __builtin_amdgcn_global_load_lds(                                          \
        (const __attribute__((address_space(1))) void*)(gp),                   \
        (__attribute__((address_space(3))) void*)(lp), 16, 0, 0)

// ---------------------------------------------------------------------------
// prep: one wave per row (x rows then y rows). Scale by exp(-0.5*lbw), cast
// bf16, accumulate row norm from the ROUNDED values (keeps pdist >= 0).
// ---------------------------------------------------------------------------
__global__ __launch_bounds__(256) void ard_prep(
    const float* __restrict__ x, const float* __restrict__ y,
    const float* __restrict__ lbw,
    __hip_bfloat16* __restrict__ xw, __hip_bfloat16* __restrict__ yw,
    float* __restrict__ x2, float* __restrict__ y2)
{
    const int lane = threadIdx.x & 63;
    const int row  = blockIdx.x * 4 + (threadIdx.x >> 6);   // 0 .. N+M-1

    const float* src;
    __hip_bfloat16* dst;
    float* nrm;
    if (row < NN) {
        src = x + (size_t)row * DD;
        dst = xw + (size_t)row * DD;
        nrm = x2 + row;
    } else {
        const int r = row - NN;
        src = y + (size_t)r * DD;
        dst = yw + (size_t)r * DD;
        nrm = y2 + r;
    }

    const float4 v  = reinterpret_cast<const float4*>(src)[lane];
    const float4 lw = reinterpret_cast<const float4*>(lbw)[lane];

    float wv[4];
    wv[0] = v.x * __expf(-0.5f * lw.x);
    wv[1] = v.y * __expf(-0.5f * lw.y);
    wv[2] = v.z * __expf(-0.5f * lw.z);
    wv[3] = v.w * __expf(-0.5f * lw.w);

    __hip_bfloat16 h[4];
    float s = 0.0f;
#pragma unroll
    for (int j = 0; j < 4; ++j) {
        h[j] = __float2bfloat16(wv[j]);
        const float f = __bfloat162float(h[j]);
        s += f * f;
    }

    reinterpret_cast<uint2*>(dst)[lane] = *reinterpret_cast<uint2*>(h);

#pragma unroll
    for (int off = 32; off > 0; off >>= 1) s += __shfl_down(s, off);
    if (lane == 0) *nrm = s;
}

// ---------------------------------------------------------------------------
// GEMM + fused epilogue. 8 waves; wave w owns rows 0..31 x cols [w*64,w*64+64)
// as 2x4 frags of mfma_f32_16x16x32_bf16 with OPERANDS SWAPPED (y-frag in
// slot A):  D "col" (lane&15) -> output ROW;  D "row" ((lane>>4)*4+reg) ->
// output COL, 4 consecutive.
//
// LDS: double-buffered, rows of 64 B; logical byte-col c of row r lives at
// r*64 + (c ^ ((r&3)<<4)); swizzle applied on the per-lane GLOBAL source
// (rule #21), LDS dest linear. Same bank audit as R6 (conflict-free b128).
// ---------------------------------------------------------------------------
__global__ __launch_bounds__(512) void ard_gemm(
    const __hip_bfloat16* __restrict__ A,   // xw [N][D]
    const __hip_bfloat16* __restrict__ B,   // yw [M][D]
    const float* __restrict__ x2, const float* __restrict__ y2,
    float* __restrict__ out)                // [N][M]
{
    __shared__ __align__(16) char sAb[2][BM * 64];   // 2 x 2 KB
    __shared__ __align__(16) char sBb[2][BN * 64];   // 2 x 32 KB

    const int tid  = threadIdx.x;
    const int lane = tid & 63;
    const int wid  = tid >> 6;     // 0..7

    // XCD slab mapping: XCD x (= bid%8, round-robin dispatch) owns row-slab
    // [x*512, x*512+512); within it, o=bid/8 sweeps bi (o>>3) with bj fastest.
    const int bid = blockIdx.x;
    const int xcd = bid & 7;
    const int o   = bid >> 3;
    const int bi  = xcd * 16 + (o >> 3);   // 0..127 (32-row band)
    const int bj  = o & 7;                 // 0..7   (512-col band)

    const size_t arow0 = (size_t)bi * BM;
    const size_t brow0 = (size_t)bj * BN;

    // staging: one GLOAD16 = 1 KB = 16 rows x 64 B. lane -> row r0+(lane>>2),
    // 16B slot lane&3.
    const int crow = lane >> 2;          // 0..15 row within 16-row chunk
    const int slot = lane & 3;           // 16B slot within 64B row

    auto stage = [&](int buf, int kt) {
        const int colb = kt * 64;        // global byte-col base of this K-step
        const int lcb  = colb + ((slot * 16) ^ ((crow & 3) << 4));
        // B: wave w stages rows [w*64, w*64+64) -> 4 gloads
#pragma unroll
        for (int t = 0; t < 4; ++t) {
            const int r   = wid * 64 + t * 16;               // wave-uniform
            const int row = r + crow;                        // per-lane
            GLOAD16((const char*)(B + (brow0 + row) * DD) + lcb, sBb[buf] + r * 64);
        }
        // A: waves 0,1 stage rows [wid*16, wid*16+16)
        if (wid < 2) {
            const int r   = wid * 16;
            const int row = r + crow;
            GLOAD16((const char*)(A + (arow0 + row) * DD) + lcb, sAb[buf] + r * 64);
        }
    };

    f32x4 acc[2][4] = {};
    const int frow = lane & 15;          // fragment row within 16
    const int fkb  = (lane >> 4) * 16;   // K byte sub-offset within 64B row
    const int rdo  = fkb ^ ((frow & 3) << 4);   // swizzled per-lane row offset

    stage(0, 0);
    __syncthreads();   // buf0 staged

#pragma unroll
    for (int kt = 0; kt < NKT; ++kt) {
        const int cur = kt & 1;
        if (kt + 1 < NKT) stage(cur ^ 1, kt + 1);   // prefetch under MFMA

        bf16x8 a[2], b[4];
#pragma unroll
        for (int m = 0; m < 2; ++m) {
            const int row = m * 16 + frow;
            a[m] = *reinterpret_cast<const bf16x8*>(sAb[cur] + row * 64 + rdo);
        }
#pragma unroll
        for (int n = 0; n < 4; ++n) {
            const int row = wid * 64 + n * 16 + frow;
            b[n] = *reinterpret_cast<const bf16x8*>(sBb[cur] + row * 64 + rdo);
        }
#pragma unroll
        for (int m = 0; m < 2; ++m)
#pragma unroll
            for (int n = 0; n < 4; ++n)
                acc[m][n] = __builtin_amdgcn_mfma_f32_16x16x32_bf16(
                    b[n], a[m], acc[m][n], 0, 0, 0);   // SWAPPED

        __syncthreads();   // next buf staged; cur consumed before overwrite
    }

    // epilogue: out row = bi*32 + m*16 + (lane&15);
    //           cols   = bj*512 + wid*64 + n*16 + (lane>>4)*4 .. +3
    const int row0 = bi * BM;
    const int col0 = bj * BN + wid * 64;
    const int cl   = lane & 15;
    const int rsub = (lane >> 4) * 4;

#pragma unroll
    for (int m = 0; m < 2; ++m) {
        const int r = row0 + m * 16 + cl;
        const float xv = x2[r];
        float* orow = out + (size_t)r * MM;
#pragma unroll
        for (int n = 0; n < 4; ++n) {
            const int c = col0 + n * 16 + rsub;
            const float4 yv = *reinterpret_cast<const float4*>(y2 + c);
            f32x4 ov;
            ov.x = __expf(-0.5f * fmaxf(xv + yv.x - 2.0f * acc[m][n][0], 0.0f));
            ov.y = __expf(-0.5f * fmaxf(xv + yv.y - 2.0f * acc[m][n][1], 0.0f));
            ov.z = __expf(-0.5f * fmaxf(xv + yv.z - 2.0f * acc[m][n][2], 0.0f));
            ov.w = __expf(-0.5f * fmaxf(xv + yv.w - 2.0f * acc[m][n][3], 0.0f));
            *reinterpret_cast<f32x4*>(orow + c) = ov;
        }
    }
}

extern "C" void kernel_launch(void* const* d_in, const int* in_sizes, int n_in,
                              void* d_out, int out_size, void* d_ws, size_t ws_size,
                              hipStream_t stream) {
    const float* x   = (const float*)d_in[0];
    const float* y   = (const float*)d_in[1];
    const float* lbw = (const float*)d_in[2];
    float* out = (float*)d_out;

    char* ws = (char*)d_ws;
    __hip_bfloat16* xw = (__hip_bfloat16*)ws;                             // 2 MB
    __hip_bfloat16* yw = (__hip_bfloat16*)(ws + (size_t)2 * 1024 * 1024); // 2 MB
    float* x2 = (float*)(ws + (size_t)4 * 1024 * 1024);                   // 16 KB
    float* y2 = (float*)(ws + (size_t)4 * 1024 * 1024 + 16384);           // 16 KB

    ard_prep<<<(NN + MM) / 4, 256, 0, stream>>>(x, y, lbw, xw, yw, x2, y2);

    // 1024 blocks: 8 XCD slabs x 16 row-bands x 8 col-bands
    ard_gemm<<<1024, 512, 0, stream>>>(xw, yw, x2, y2, out);
}